// Round 3
// baseline (6465.141 us; speedup 1.0000x reference)
//
#include <hip/hip_runtime.h>

#define N_ATOMS 131072
#define M_NBR 12
#define ORIG_F 92
#define AF 64
#define NCONV 3
#define N0_CRYS 1024
#define FIN 169
#define C2 128
#define BN_EPS 1e-5f

__device__ __forceinline__ float sigmoidf_(float t) {
    return 1.0f / (1.0f + __expf(-t));
}
__device__ __forceinline__ float softplusf_(float t) {
    return fmaxf(t, 0.0f) + __logf(1.0f + __expf(-fabsf(t)));
}
__device__ __forceinline__ void fma4(float4& a, float s, float4 w) {
    a.x = fmaf(s, w.x, a.x); a.y = fmaf(s, w.y, a.y);
    a.z = fmaf(s, w.z, a.z); a.w = fmaf(s, w.w, a.w);
}

// ---------------- embed: one thread per (n,f) ----------------
__global__ __launch_bounds__(256) void k_embed(const float* __restrict__ af,
                                               const float* __restrict__ W,
                                               const float* __restrict__ b,
                                               float* __restrict__ x) {
    int i = blockIdx.x * 256 + threadIdx.x;   // i < N*64
    int n = i >> 6, f = i & 63;
    float acc = b[f];
    for (int k = 0; k < ORIG_F; ++k)
        acc = fmaf(af[(size_t)n * ORIG_F + k], W[k * AF + f], acc);
    x[i] = acc;
}

// ---------------- gemm: gated[n,m,:] = concat(x[n], x[idx[n,m]], nbrf[n,m]) @ W + b
// block = 256 threads = 2 atoms x (32 channel-groups x 4 m-groups)
__global__ __launch_bounds__(256) void k_gemm(const float* __restrict__ x,
                                              const float* __restrict__ nbrf,
                                              const int* __restrict__ nidx,
                                              const float* __restrict__ Wl,
                                              const float* __restrict__ bl,
                                              float* __restrict__ gated) {
    __shared__ float tot[2][12][172];
    const int tid = threadIdx.x;
    const int at  = tid >> 7;        // atom within block
    const int t   = tid & 127;
    const int cg  = t & 31;          // channels 4cg..4cg+3
    const int mg  = t >> 5;          // m in {mg, mg+4, mg+8}
    const int n0  = blockIdx.x * 2;

    // stage self + gathered neighbor rows (the literal concat, per m)
    for (int i = tid; i < 2 * 12 * 64; i += 256) {
        int a = i / 768, r = i - a * 768, m = r >> 6, k = r & 63;
        int n = n0 + a;
        tot[a][m][k] = x[(size_t)n * 64 + k];
        int gi = nidx[n * 12 + m];
        tot[a][m][64 + k] = x[(size_t)gi * 64 + k];
    }
    // stage nbr_fea rows
    for (int i = tid; i < 2 * 12 * 41; i += 256) {
        int a = i / 492, r = i - a * 492, m = r / 41, k = r - m * 41;
        tot[a][m][128 + k] = nbrf[((size_t)(n0 + a) * 12 + m) * 41 + k];
    }
    __syncthreads();

    const float4* W4 = (const float4*)Wl;         // [169][32] float4
    const float4 bias = ((const float4*)bl)[cg];
    float4 acc0 = bias, acc1 = bias, acc2 = bias;
    for (int k = 0; k < FIN; ++k) {
        float4 w = W4[k * 32 + cg];
        float r0 = tot[at][mg][k];
        float r1 = tot[at][mg + 4][k];
        float r2 = tot[at][mg + 8][k];
        fma4(acc0, r0, w);
        fma4(acc1, r1, w);
        fma4(acc2, r2, w);
    }
    int n = n0 + at;
    ((float4*)(gated + ((size_t)n * 12 + mg    ) * 128))[cg] = acc0;
    ((float4*)(gated + ((size_t)n * 12 + mg + 4) * 128))[cg] = acc1;
    ((float4*)(gated + ((size_t)n * 12 + mg + 8) * 128))[cg] = acc2;
}

// ---------------- bn1 stats: per-channel sum / sumsq over all N*M rows --------
__global__ __launch_bounds__(256) void k_bn1stats(const float* __restrict__ gated,
                                                  double* __restrict__ stats) {
    const int tid = threadIdx.x;
    const int ch = tid & 127, half = tid >> 7;
    const long long rows_per_block = (long long)N_ATOMS * M_NBR / 2048;  // 768
    long long r0 = (long long)blockIdx.x * rows_per_block + half * (rows_per_block / 2);
    float s = 0.0f, q = 0.0f;
    for (long long r = r0; r < r0 + rows_per_block / 2; ++r) {
        float v = gated[r * 128 + ch];
        s += v; q = fmaf(v, v, q);
    }
    __shared__ float red[512];
    red[tid] = s; red[256 + tid] = q;
    __syncthreads();
    if (tid < 128) {
        double ss = (double)red[tid] + (double)red[tid + 128];
        double qq = (double)red[256 + tid] + (double)red[256 + tid + 128];
        atomicAdd(&stats[ch], ss);
        atomicAdd(&stats[128 + ch], qq);
    }
}

// ---------------- convB: BN1 + sigmoid*softplus + sum over M (+ BN2 stats) ----
__global__ __launch_bounds__(256) void k_convB(const float* __restrict__ gated,
                                               const float* __restrict__ g1,
                                               const float* __restrict__ be1,
                                               double* __restrict__ stats,
                                               float* __restrict__ ns) {
    const int tid = threadIdx.x;
    const int f = tid & 63;
    const int ag = tid >> 6;
    const double cnt1 = (double)N_ATOMS * M_NBR;
    double m1d = stats[f] / cnt1;
    double v1d = stats[128 + f] / cnt1 - m1d * m1d;
    double m2d = stats[64 + f] / cnt1;
    double v2d = stats[192 + f] / cnt1 - m2d * m2d;
    float i1 = rsqrtf((float)v1d + BN_EPS);
    float i2 = rsqrtf((float)v2d + BN_EPS);
    float A1 = g1[f] * i1,      B1 = be1[f]      - A1 * (float)m1d;
    float A2 = g1[64 + f] * i2, B2 = be1[64 + f] - A2 * (float)m2d;

    float lsum = 0.0f, lsq = 0.0f;
    for (int n = blockIdx.x * 4 + ag; n < N_ATOMS; n += gridDim.x * 4) {
        const float* gp = gated + (size_t)n * (M_NBR * C2);
        float acc = 0.0f;
#pragma unroll
        for (int m = 0; m < M_NBR; ++m) {
            float ga = gp[m * 128 + f];
            float gb = gp[m * 128 + 64 + f];
            float flt = sigmoidf_(fmaf(A1, ga, B1));
            float cor = softplusf_(fmaf(A2, gb, B2));
            acc = fmaf(flt, cor, acc);
        }
        ns[(size_t)n * 64 + f] = acc;
        lsum += acc; lsq = fmaf(acc, acc, lsq);
    }
    __shared__ float r[512];
    r[tid] = lsum; r[256 + tid] = lsq;
    __syncthreads();
    if (tid < 64) {
        double s = (double)r[tid] + r[tid + 64] + r[tid + 128] + r[tid + 192];
        double q = (double)r[256 + tid] + r[256 + tid + 64] + r[256 + tid + 128] + r[256 + tid + 192];
        atomicAdd(&stats[256 + tid], s);
        atomicAdd(&stats[320 + tid], q);
    }
}

// ---------------- convC: x = softplus(x + BN2(ns)) ----------------
__global__ __launch_bounds__(256) void k_convC(float* __restrict__ x,
                                               const float* __restrict__ ns,
                                               const float* __restrict__ g2,
                                               const float* __restrict__ be2,
                                               const double* __restrict__ stats) {
    const int i = blockIdx.x * 256 + threadIdx.x;
    const int f = i & 63;
    const double cnt = (double)N_ATOMS;
    double md = stats[256 + f] / cnt;
    double vd = stats[320 + f] / cnt - md * md;
    float inv = rsqrtf((float)vd + BN_EPS);
    float A = g2[f] * inv, B = be2[f] - A * (float)md;
    float t = x[i] + fmaf(A, ns[i], B);
    x[i] = softplusf_(t);
}

// ---------------- pool: per-crystal mean (sorted idx, binary search) ---------
__global__ __launch_bounds__(64) void k_pool(const float* __restrict__ x,
                                             const int* __restrict__ cidx,
                                             float* __restrict__ crys) {
    const int s = blockIdx.x;
    const int f = threadIdx.x;
    int lo = 0, hi = N_ATOMS;
    while (lo < hi) { int mid = (lo + hi) >> 1; if (cidx[mid] < s) lo = mid + 1; else hi = mid; }
    int lo2 = lo, hi2 = N_ATOMS;
    while (lo2 < hi2) { int mid = (lo2 + hi2) >> 1; if (cidx[mid] < s + 1) lo2 = mid + 1; else hi2 = mid; }
    float sum = 0.0f;
    for (int i = lo; i < lo2; ++i) sum += x[(size_t)i * 64 + f];
    float cnt = fmaxf((float)(lo2 - lo), 1.0f);
    crys[s * 64 + f] = sum / cnt;
}

// ---------------- head ----------------
__global__ __launch_bounds__(128) void k_head(const float* __restrict__ crys,
                                              const float* __restrict__ W1,
                                              const float* __restrict__ b1,
                                              const float* __restrict__ W2,
                                              const float* __restrict__ b2,
                                              float* __restrict__ out) {
    __shared__ float a_sh[64];
    __shared__ float r_sh[128];
    const int n = blockIdx.x;
    const int tid = threadIdx.x;
    if (tid < 64) a_sh[tid] = softplusf_(crys[n * 64 + tid]);
    __syncthreads();
    for (int p = 0; p < 2; ++p) {
        float acc = b1[p * 128 + tid];
#pragma unroll
        for (int f2 = 0; f2 < 64; ++f2)
            acc = fmaf(a_sh[f2], W1[(p * 64 + f2) * 128 + tid], acc);
        float contrib = softplusf_(acc) * W2[p * 128 + tid];
        r_sh[tid] = contrib;
        __syncthreads();
        for (int sft = 64; sft > 0; sft >>= 1) {
            if (tid < sft) r_sh[tid] += r_sh[tid + sft];
            __syncthreads();
        }
        if (tid == 0) out[n * 2 + p] = r_sh[0] + b2[p];
        __syncthreads();
    }
}

extern "C" void kernel_launch(void* const* d_in, const int* in_sizes, int n_in,
                              void* d_out, int out_size, void* d_ws, size_t ws_size,
                              hipStream_t stream) {
    const float* atom_fea = (const float*)d_in[0];
    const float* nbr_fea  = (const float*)d_in[1];
    const float* W_embed  = (const float*)d_in[2];
    const float* b_embed  = (const float*)d_in[3];
    const float* conv_W   = (const float*)d_in[4];
    const float* conv_b   = (const float*)d_in[5];
    const float* conv_g1  = (const float*)d_in[6];
    const float* conv_be1 = (const float*)d_in[7];
    const float* conv_g2  = (const float*)d_in[8];
    const float* conv_be2 = (const float*)d_in[9];
    const float* head_W1  = (const float*)d_in[10];
    const float* head_b1  = (const float*)d_in[11];
    const float* head_W2  = (const float*)d_in[12];
    const float* head_b2  = (const float*)d_in[13];
    const int*   nidx     = (const int*)d_in[14];
    const int*   cryst    = (const int*)d_in[15];

    // workspace layout
    char* w = (char*)d_ws;
    float*  x     = (float*)w;                       // 33,554,432 B
    float*  gated = (float*)(w + 33554432);          // 805,306,368 B
    float*  ns    = (float*)(w + 838860800);         // 33,554,432 B
    double* stats = (double*)(w + 872415232);        // 3*384*8 = 9,216 B
    const size_t required = 872415232ull + 9216ull;
    if (ws_size < required) {
        hipMemsetAsync(d_out, 0x7F, 4, stream);
        return;
    }

    hipMemsetAsync(stats, 0, NCONV * 384 * sizeof(double), stream);

    k_embed<<<N_ATOMS * AF / 256, 256, 0, stream>>>(atom_fea, W_embed, b_embed, x);

    for (int l = 0; l < NCONV; ++l) {
        double* st = stats + l * 384;
        k_gemm<<<N_ATOMS / 2, 256, 0, stream>>>(x, nbr_fea, nidx,
                                                conv_W + (size_t)l * FIN * C2,
                                                conv_b + l * C2, gated);
        k_bn1stats<<<2048, 256, 0, stream>>>(gated, st);
        k_convB<<<8192, 256, 0, stream>>>(gated, conv_g1 + l * C2, conv_be1 + l * C2, st, ns);
        k_convC<<<N_ATOMS * AF / 256, 256, 0, stream>>>(x, ns, conv_g2 + l * AF, conv_be2 + l * AF, st);
    }

    float* crys = (float*)d_out + N0_CRYS * 2;   // crys_fea after out
    k_pool<<<N0_CRYS, 64, 0, stream>>>(x, cryst, crys);
    k_head<<<N0_CRYS, 128, 0, stream>>>(crys, head_W1, head_b1, head_W2, head_b2, (float*)d_out);
}

// Round 4
// 2503.023 us; speedup vs baseline: 2.5829x; 2.5829x over previous
//
#include <hip/hip_runtime.h>

#define N_ATOMS 131072
#define M_NBR 12
#define ORIG_F 92
#define AF 64
#define NCONV 3
#define N0_CRYS 1024
#define FIN 169
#define C2 128
#define KPAD 192
#define BN_EPS 1e-5f
#define RB_TOTAL (N_ATOMS * M_NBR / 64)   // 24576 row-blocks of 64

typedef _Float16 f16;
typedef _Float16 half8 __attribute__((ext_vector_type(8)));
typedef float f32x4 __attribute__((ext_vector_type(4)));

__device__ __forceinline__ float sigmoidf_(float t) {
    return 1.0f / (1.0f + __expf(-t));
}
__device__ __forceinline__ float softplusf_(float t) {
    return fmaxf(t, 0.0f) + __logf(1.0f + __expf(-fabsf(t)));
}

// ---------------- embed: x = atom_fea @ W_embed + b  (writes fp32 + f16) -----
__global__ __launch_bounds__(256) void k_embed(const float* __restrict__ af,
                                               const float* __restrict__ W,
                                               const float* __restrict__ b,
                                               float* __restrict__ x,
                                               f16* __restrict__ xh) {
    int i = blockIdx.x * 256 + threadIdx.x;   // i < N*64
    int n = i >> 6, f = i & 63;
    float acc = b[f];
    for (int k = 0; k < ORIG_F; ++k)
        acc = fmaf(af[(size_t)n * ORIG_F + k], W[k * AF + f], acc);
    x[i] = acc;
    xh[i] = (f16)acc;
}

// ---------------- cvt nbr_fea -> f16 padded [N*M][44] ----------------
__global__ __launch_bounds__(256) void k_cvt_nbrf(const float* __restrict__ nf,
                                                  f16* __restrict__ nfh) {
    const int r0 = blockIdx.x * 16;
    for (int i = threadIdx.x; i < 16 * 44; i += 256) {
        int r = i / 44, k = i - r * 44;
        size_t row = (size_t)(r0 + r);
        nfh[row * 44 + k] = (k < 41) ? (f16)nf[row * 41 + k] : (f16)0.0f;
    }
}

// ---------------- prep W^T: Wt[c][k] f16, k padded to 192 ----------------
__global__ __launch_bounds__(256) void k_prepW(const float* __restrict__ W,
                                               f16* __restrict__ Wt) {
    int i = blockIdx.x * 256 + threadIdx.x;    // i < 128*192
    if (i >= C2 * KPAD) return;
    int c = i / KPAD, k = i - c * KPAD;
    Wt[i] = (k < FIN) ? (f16)W[k * C2 + c] : (f16)0.0f;
}

// ---------------- MFMA gemm: gated = concat-rows @ W + b  (+ fused BN1 stats)
// block = 256 (4 waves). Block tile: 64 rows x 128 cols.
// Wave (w>>1 = row-half, w&1 = col-half): 32 rows x 64 cols = 2x4 MFMA frags.
// B fragments live in registers (96 VGPR/lane), A tile staged in LDS.
__global__ __launch_bounds__(256) void k_gemmh(const f16* __restrict__ xh,
                                               const f16* __restrict__ nfh,
                                               const int* __restrict__ nidx,
                                               const f16* __restrict__ Wt,
                                               const float* __restrict__ bl,
                                               f16* __restrict__ gated,
                                               float* __restrict__ stats) {
    __shared__ unsigned short Ash[64 * 200];   // 64 rows, stride 200 f16 (bank-spread)
    __shared__ int ns_[64], gs_[64];
    __shared__ float redS[128], redQ[128];

    const int tid = threadIdx.x;
    const int wv = tid >> 6;
    const int lane = tid & 63;
    const int quad = lane >> 4;
    const int l16 = lane & 15;
    const int rhalf = wv >> 1;
    const int c0w = (wv & 1) * 64;

    if (tid < 128) { redS[tid] = 0.0f; redQ[tid] = 0.0f; }
    // zero pad cols 172..199 once (never overwritten by staging)
    for (int i = tid; i < 64 * 7; i += 256) {
        int r = i / 7, t = i - r * 7;
        *(ushort4*)&Ash[r * 200 + 172 + t * 4] = make_ushort4(0, 0, 0, 0);
    }

    half8 Bf[6][4];
    float bias_[4];
    float ssum[4] = {0, 0, 0, 0}, ssq[4] = {0, 0, 0, 0};
#pragma unroll
    for (int ct = 0; ct < 4; ++ct) {
        int c = c0w + ct * 16 + l16;
        bias_[ct] = bl[c];
#pragma unroll
        for (int kc = 0; kc < 6; ++kc)
            Bf[kc][ct] = *(const half8*)&Wt[c * KPAD + kc * 32 + quad * 8];
    }

    for (int rb = blockIdx.x; rb < RB_TOTAL; rb += gridDim.x) {
        const int r0 = rb * 64;
        __syncthreads();                       // protect Ash from prior iter reads
        if (tid < 64) {
            int rr = r0 + tid;
            ns_[tid] = rr / 12;
            gs_[tid] = nidx[rr];
        }
        __syncthreads();
        // stage: self (cols 0..63) + gathered neighbor (64..127), 4 f16 per step
        for (int i = tid; i < 64 * 32; i += 256) {
            int r = i >> 5, sg = i & 31;
            const f16* src = (sg < 16) ? (xh + (size_t)ns_[r] * 64 + sg * 4)
                                       : (xh + (size_t)gs_[r] * 64 + (sg - 16) * 4);
            *(ushort4*)&Ash[r * 200 + sg * 4] = *(const ushort4*)src;
        }
        // stage nbr_fea (cols 128..171, f16-padded source)
        for (int i = tid; i < 64 * 11; i += 256) {
            int r = i / 11, j = i - r * 11;
            *(ushort4*)&Ash[r * 200 + 128 + j * 4] =
                *(const ushort4*)&nfh[(size_t)(r0 + r) * 44 + j * 4];
        }
        __syncthreads();

        f32x4 acc[2][4];
#pragma unroll
        for (int rf = 0; rf < 2; ++rf)
#pragma unroll
            for (int ct = 0; ct < 4; ++ct) acc[rf][ct] = (f32x4){0, 0, 0, 0};

#pragma unroll
        for (int kc = 0; kc < 6; ++kc) {
            half8 a0 = *(half8*)&Ash[(rhalf * 32 + l16) * 200 + kc * 32 + quad * 8];
            half8 a1 = *(half8*)&Ash[(rhalf * 32 + 16 + l16) * 200 + kc * 32 + quad * 8];
#pragma unroll
            for (int ct = 0; ct < 4; ++ct) {
                acc[0][ct] = __builtin_amdgcn_mfma_f32_16x16x32_f16(a0, Bf[kc][ct], acc[0][ct], 0, 0, 0);
                acc[1][ct] = __builtin_amdgcn_mfma_f32_16x16x32_f16(a1, Bf[kc][ct], acc[1][ct], 0, 0, 0);
            }
        }

        // epilogue: C layout col=lane&15, row=quad*4+e
#pragma unroll
        for (int rf = 0; rf < 2; ++rf) {
            int rbase = r0 + rhalf * 32 + rf * 16 + quad * 4;
#pragma unroll
            for (int ct = 0; ct < 4; ++ct) {
                int c = c0w + ct * 16 + l16;
#pragma unroll
                for (int e = 0; e < 4; ++e) {
                    float v = acc[rf][ct][e] + bias_[ct];
                    gated[(size_t)(rbase + e) * 128 + c] = (f16)v;
                    ssum[ct] += v;
                    ssq[ct] = fmaf(v, v, ssq[ct]);
                }
            }
        }
    }

    // BN1 stats: quad-reduce, LDS-reduce, one global atomic per channel per block
#pragma unroll
    for (int ct = 0; ct < 4; ++ct) {
        float s = ssum[ct], q = ssq[ct];
        s += __shfl_xor(s, 16); s += __shfl_xor(s, 32);
        q += __shfl_xor(q, 16); q += __shfl_xor(q, 32);
        if (quad == 0) {
            atomicAdd(&redS[c0w + ct * 16 + l16], s);
            atomicAdd(&redQ[c0w + ct * 16 + l16], q);
        }
    }
    __syncthreads();
    if (tid < 128) {
        atomicAdd(&stats[tid], redS[tid]);
        atomicAdd(&stats[128 + tid], redQ[tid]);
    }
}

// ---------------- convB: BN1 + sigmoid*softplus + sum over M (+ BN2 stats) ----
__global__ __launch_bounds__(256) void k_convB(const f16* __restrict__ gated,
                                               const float* __restrict__ g1,
                                               const float* __restrict__ be1,
                                               float* __restrict__ stats,
                                               float* __restrict__ ns) {
    const int tid = threadIdx.x;
    const int f = tid & 63;
    const int ag = tid >> 6;
    const float cnt1 = (float)N_ATOMS * M_NBR;
    float m1 = stats[f] / cnt1;
    float v1 = stats[128 + f] / cnt1 - m1 * m1;
    float m2 = stats[64 + f] / cnt1;
    float v2 = stats[192 + f] / cnt1 - m2 * m2;
    float i1 = rsqrtf(v1 + BN_EPS);
    float i2 = rsqrtf(v2 + BN_EPS);
    float A1 = g1[f] * i1,      B1 = be1[f]      - A1 * m1;
    float A2 = g1[64 + f] * i2, B2 = be1[64 + f] - A2 * m2;

    float lsum = 0.0f, lsq = 0.0f;
    for (int n = blockIdx.x * 4 + ag; n < N_ATOMS; n += gridDim.x * 4) {
        const f16* gp = gated + (size_t)n * (M_NBR * C2);
        float acc = 0.0f;
#pragma unroll
        for (int m = 0; m < M_NBR; ++m) {
            float ga = (float)gp[m * 128 + f];
            float gb = (float)gp[m * 128 + 64 + f];
            float flt = sigmoidf_(fmaf(A1, ga, B1));
            float cor = softplusf_(fmaf(A2, gb, B2));
            acc = fmaf(flt, cor, acc);
        }
        ns[(size_t)n * 64 + f] = acc;
        lsum += acc; lsq = fmaf(acc, acc, lsq);
    }
    __shared__ float r[512];
    r[tid] = lsum; r[256 + tid] = lsq;
    __syncthreads();
    if (tid < 64) {
        float s = r[tid] + r[tid + 64] + r[tid + 128] + r[tid + 192];
        float q = r[256 + tid] + r[256 + tid + 64] + r[256 + tid + 128] + r[256 + tid + 192];
        atomicAdd(&stats[256 + tid], s);
        atomicAdd(&stats[320 + tid], q);
    }
}

// ---------------- convC: x = softplus(x + BN2(ns))  (writes fp32 + f16) ------
__global__ __launch_bounds__(256) void k_convC(float* __restrict__ x,
                                               f16* __restrict__ xh,
                                               const float* __restrict__ ns,
                                               const float* __restrict__ g2,
                                               const float* __restrict__ be2,
                                               const float* __restrict__ stats) {
    const int i = blockIdx.x * 256 + threadIdx.x;
    const int f = i & 63;
    const float cnt = (float)N_ATOMS;
    float m = stats[256 + f] / cnt;
    float v = stats[320 + f] / cnt - m * m;
    float inv = rsqrtf(v + BN_EPS);
    float A = g2[f] * inv, B = be2[f] - A * m;
    float t = x[i] + fmaf(A, ns[i], B);
    float o = softplusf_(t);
    x[i] = o;
    xh[i] = (f16)o;
}

// ---------------- pool: per-crystal mean (sorted idx, binary search) ---------
__global__ __launch_bounds__(64) void k_pool(const float* __restrict__ x,
                                             const int* __restrict__ cidx,
                                             float* __restrict__ crys) {
    const int s = blockIdx.x;
    const int f = threadIdx.x;
    int lo = 0, hi = N_ATOMS;
    while (lo < hi) { int mid = (lo + hi) >> 1; if (cidx[mid] < s) lo = mid + 1; else hi = mid; }
    int lo2 = lo, hi2 = N_ATOMS;
    while (lo2 < hi2) { int mid = (lo2 + hi2) >> 1; if (cidx[mid] < s + 1) lo2 = mid + 1; else hi2 = mid; }
    float sum = 0.0f;
    for (int i = lo; i < lo2; ++i) sum += x[(size_t)i * 64 + f];
    float cnt = fmaxf((float)(lo2 - lo), 1.0f);
    crys[s * 64 + f] = sum / cnt;
}

// ---------------- head ----------------
__global__ __launch_bounds__(128) void k_head(const float* __restrict__ crys,
                                              const float* __restrict__ W1,
                                              const float* __restrict__ b1,
                                              const float* __restrict__ W2,
                                              const float* __restrict__ b2,
                                              float* __restrict__ out) {
    __shared__ float a_sh[64];
    __shared__ float r_sh[128];
    const int n = blockIdx.x;
    const int tid = threadIdx.x;
    if (tid < 64) a_sh[tid] = softplusf_(crys[n * 64 + tid]);
    __syncthreads();
    for (int p = 0; p < 2; ++p) {
        float acc = b1[p * 128 + tid];
#pragma unroll
        for (int f2 = 0; f2 < 64; ++f2)
            acc = fmaf(a_sh[f2], W1[(p * 64 + f2) * 128 + tid], acc);
        float contrib = softplusf_(acc) * W2[p * 128 + tid];
        r_sh[tid] = contrib;
        __syncthreads();
        for (int sft = 64; sft > 0; sft >>= 1) {
            if (tid < sft) r_sh[tid] += r_sh[tid + sft];
            __syncthreads();
        }
        if (tid == 0) out[n * 2 + p] = r_sh[0] + b2[p];
        __syncthreads();
    }
}

extern "C" void kernel_launch(void* const* d_in, const int* in_sizes, int n_in,
                              void* d_out, int out_size, void* d_ws, size_t ws_size,
                              hipStream_t stream) {
    const float* atom_fea = (const float*)d_in[0];
    const float* nbr_fea  = (const float*)d_in[1];
    const float* W_embed  = (const float*)d_in[2];
    const float* b_embed  = (const float*)d_in[3];
    const float* conv_W   = (const float*)d_in[4];
    const float* conv_b   = (const float*)d_in[5];
    const float* conv_g1  = (const float*)d_in[6];
    const float* conv_be1 = (const float*)d_in[7];
    const float* conv_g2  = (const float*)d_in[8];
    const float* conv_be2 = (const float*)d_in[9];
    const float* head_W1  = (const float*)d_in[10];
    const float* head_b1  = (const float*)d_in[11];
    const float* head_W2  = (const float*)d_in[12];
    const float* head_b2  = (const float*)d_in[13];
    const int*   nidx     = (const int*)d_in[14];
    const int*   cryst    = (const int*)d_in[15];

    // workspace layout
    char* w = (char*)d_ws;
    float* x      = (float*)w;                        //  33,554,432
    f16*   xh     = (f16*)(w + 33554432);             //  16,777,216
    f16*   gated  = (f16*)(w + 50331648);             // 402,653,184
    float* ns     = (float*)(w + 452984832);          //  33,554,432
    f16*   nfh    = (f16*)(w + 486539264);            // 138,412,032
    f16*   Wt     = (f16*)(w + 624951296);            //      49,152
    float* stats  = (float*)(w + 625000448);          //       4,608
    const size_t required = 625000448ull + 4608ull;
    if (ws_size < required) {
        hipMemsetAsync(d_out, 0x7F, 4, stream);
        return;
    }

    hipMemsetAsync(stats, 0, NCONV * 384 * sizeof(float), stream);

    k_cvt_nbrf<<<N_ATOMS * M_NBR / 16, 256, 0, stream>>>(nbr_fea, nfh);
    k_embed<<<N_ATOMS * AF / 256, 256, 0, stream>>>(atom_fea, W_embed, b_embed, x, xh);

    for (int l = 0; l < NCONV; ++l) {
        float* st = stats + l * 384;
        k_prepW<<<(C2 * KPAD + 255) / 256, 256, 0, stream>>>(conv_W + (size_t)l * FIN * C2, Wt);
        k_gemmh<<<1024, 256, 0, stream>>>(xh, nfh, nidx, Wt, conv_b + l * C2, gated, st);
        k_convB<<<8192, 256, 0, stream>>>(gated, conv_g1 + l * C2, conv_be1 + l * C2, st, ns);
        k_convC<<<N_ATOMS * AF / 256, 256, 0, stream>>>(x, xh, ns, conv_g2 + l * AF, conv_be2 + l * AF, st);
    }

    float* crys = (float*)d_out + N0_CRYS * 2;   // crys_fea follows out
    k_pool<<<N0_CRYS, 64, 0, stream>>>(x, cryst, crys);
    k_head<<<N0_CRYS, 128, 0, stream>>>(crys, head_W1, head_b1, head_W2, head_b2, (float*)d_out);
}